// Round 2
// 348.283 us; speedup vs baseline: 1.0576x; 1.0576x over previous
//
#include <hip/hip_runtime.h>
#include <hip/hip_bf16.h>

typedef __hip_bfloat16 bf16;
typedef float f32x4 __attribute__((ext_vector_type(4)));

__device__ __forceinline__ float b2f(bf16 x) { return __bfloat162float(x); }

// Inputs proved float32 (R1/R2 of prior session); bf16 path kept as insurance.
template<bool F32>
__device__ __forceinline__ float ld(const void* p, size_t i) {
  if constexpr (F32) return ((const float*)p)[i];
  else return b2f(((const bf16*)p)[i]);
}

template<bool F32>
__device__ __forceinline__ void ld4(const void* p, size_t i, float v[4]) {
  if constexpr (F32) {
    const float4 a = *(const float4*)((const float*)p + i);
    v[0]=a.x; v[1]=a.y; v[2]=a.z; v[3]=a.w;
  } else {
    union { uint2 u; bf16 h[4]; } t;
    t.u = *(const uint2*)((const bf16*)p + i);
    #pragma unroll
    for (int c = 0; c < 4; ++c) v[c] = b2f(t.h[c]);
  }
}

template<bool F32>
__device__ __forceinline__ void ld8(const void* p, size_t i, float v[8]) {
  if constexpr (F32) {
    const float4 a = *(const float4*)((const float*)p + i);
    const float4 b = *(const float4*)((const float*)p + i + 4);
    v[0]=a.x; v[1]=a.y; v[2]=a.z; v[3]=a.w;
    v[4]=b.x; v[5]=b.y; v[6]=b.z; v[7]=b.w;
  } else {
    union { uint4 u; bf16 h[8]; } t;
    t.u = *(const uint4*)((const bf16*)p + i);
    #pragma unroll
    for (int c = 0; c < 8; ++c) v[c] = b2f(t.h[c]);
  }
}

// Nontemporal variant: M1-3 are single-use per iteration; keep them from
// evicting W1-3 (read twice: k1 and k3) out of L3.
template<bool F32>
__device__ __forceinline__ void ld8nt(const void* p, size_t i, float v[8]) {
  if constexpr (F32) {
    const f32x4* q = (const f32x4*)((const float*)p + i);
    const f32x4 a = __builtin_nontemporal_load(q);
    const f32x4 b = __builtin_nontemporal_load(q + 1);
    v[0]=a[0]; v[1]=a[1]; v[2]=a[2]; v[3]=a[3];
    v[4]=b[0]; v[5]=b[1]; v[6]=b[2]; v[7]=b[3];
  } else {
    ld8<false>(p, i, v);
  }
}

__device__ __forceinline__ float plast(float Ec, float Ebl) {
  const float Eb0 = (Ebl == 0.f) ? Ec : Ebl;          // bmask logic
  const float Eb  = Eb0 * 0.95f + 0.05f * Ec;         // EMA_SPEED
  const float adv = Ec - Eb;                          // REW_SENS = 1
  const float R   = -adv * rsqrtf(adv*adv + 1e-6f);   // rms_norm size-1 axis
  return (Eb > 0.f) ? (1.f - R) : 0.f;                // plasticity * mask
}

// B=16, N=128, D=64 ; nodes = B*N = 2048
// ws layout (floats):
//   q @0 (131072) | k @131072 | err @262144 | pl @393216
//   mag @524288 (16) | stats @524304 (2) | flag @524306 (1 int)

// ---------------- Kernel 1: q, k, prediction matvecs + state_mag -------------
// 256 threads: wave w (0..3) owns j-range [w*16, w*16+16); within a wave,
// jg = lane>>4 splits 4 j's each, cq = lane&15 owns output columns 4*cq..+3.
// All W loads are float4, fully coalesced (1 KiB per wave instruction).
template<bool F32>
__device__ __forceinline__ void k1_body(
    const void* state, const void* W1, const void* W2, const void* W3,
    float* qw, float* kw, float* mag, float* out_pred,
    float* s_state, float* s_part)
{
  const int node = blockIdx.x;
  const int b = node >> 7;
  const int tid = threadIdx.x;
  const int w = tid >> 6, lane = tid & 63;
  const int jg = lane >> 4, cq = lane & 15;
  const int c0 = cq * 4;
  const size_t nb = (size_t)node * 4096;

  float w3v[4][4], w2v[4][4], w1v[4][4];
  #pragma unroll
  for (int jj = 0; jj < 4; ++jj) {
    const int j = w*16 + jg*4 + jj;
    const size_t o = nb + (size_t)j*64 + c0;
    ld4<F32>(W3, o, w3v[jj]);
    ld4<F32>(W2, o, w2v[jj]);
    ld4<F32>(W1, o, w1v[jj]);
  }
  if (tid < 64) s_state[tid] = ld<F32>(state, (size_t)node*64 + tid);
  __syncthreads();

  float aq[4] = {0,0,0,0}, ak[4] = {0,0,0,0}, ap[4] = {0,0,0,0};
  #pragma unroll
  for (int jj = 0; jj < 4; ++jj) {
    const float sj = s_state[w*16 + jg*4 + jj];
    #pragma unroll
    for (int cc = 0; cc < 4; ++cc) {
      aq[cc] += sj * w3v[jj][cc];   // q = state . W3
      ak[cc] += sj * w2v[jj][cc];   // k = state . W2
      ap[cc] += sj * w1v[jj][cc];   // raw_pred = state . W1
    }
  }
  // reduce across the 4 jg groups of this wave (lane^16, lane^32)
  #pragma unroll
  for (int cc = 0; cc < 4; ++cc) {
    aq[cc] += __shfl_xor(aq[cc], 16, 64); aq[cc] += __shfl_xor(aq[cc], 32, 64);
    ak[cc] += __shfl_xor(ak[cc], 16, 64); ak[cc] += __shfl_xor(ak[cc], 32, 64);
    ap[cc] += __shfl_xor(ap[cc], 16, 64); ap[cc] += __shfl_xor(ap[cc], 32, 64);
  }
  if (jg == 0) {
    *(float4*)&s_part[w*192 +  0 + c0] = make_float4(aq[0], aq[1], aq[2], aq[3]);
    *(float4*)&s_part[w*192 + 64 + c0] = make_float4(ak[0], ak[1], ak[2], ak[3]);
    *(float4*)&s_part[w*192 +128 + c0] = make_float4(ap[0], ap[1], ap[2], ap[3]);
  }
  if (w == 3) {
    float a = fabsf(s_state[lane]);
    #pragma unroll
    for (int s = 32; s; s >>= 1) a += __shfl_xor(a, s, 64);
    if (lane == 0) atomicAdd(&mag[b], a);
  }
  __syncthreads();
  if (tid < 192) {
    const int mat = tid >> 6, col = tid & 63;
    const float v = s_part[0*192 + mat*64 + col] + s_part[1*192 + mat*64 + col]
                  + s_part[2*192 + mat*64 + col] + s_part[3*192 + mat*64 + col];
    if (mat == 0)      qw[(size_t)node*64 + col] = v;
    else if (mat == 1) kw[(size_t)node*64 + col] = v;
    else {
      const float raw  = v - tanhf(v) * 0.6f;                 // UNTANH
      out_pred[(size_t)node*64 + col] = tanhf(raw) * 1.8477590650225735f;
    }
  }
}

__global__ __launch_bounds__(256) void k1_qkpred(
    const void* __restrict__ state,
    const void* __restrict__ W1, const void* __restrict__ W2,
    const void* __restrict__ W3,
    float* __restrict__ qw, float* __restrict__ kw,
    float* __restrict__ mag, float* __restrict__ out_pred,
    int* __restrict__ flagws)
{
  __shared__ alignas(16) float s_state[64];
  __shared__ alignas(16) float s_part[768];   // [4 waves][3 mats][64 cols]
  __shared__ int s_flag;
  const int tid = threadIdx.x;
  // inline dtype detect (replaces the old k0 kernel)
  bool huge = false;
  for (int i = tid; i < 1024; i += 256) {
    const float x = b2f(((const bf16*)state)[i]);
    if (!(fabsf(x) < 1e5f)) huge = true;    // catches NaN too
  }
  // NOTE: ballot must execute in ALL lanes (no short-circuit masking).
  const unsigned long long m = __ballot(huge);
  if (tid == 0) s_flag = 0;
  __syncthreads();
  if ((tid & 63) == 0 && m != 0ull) s_flag = 1;
  __syncthreads();
  const bool f32 = (s_flag != 0);           // huge-as-bf16 => really float32
  if (blockIdx.x == 0 && tid == 0) *flagws = f32 ? 1 : 0;   // for k2/k3
  if (f32) k1_body<true >(state, W1, W2, W3, qw, kw, mag, out_pred, s_state, s_part);
  else     k1_body<false>(state, W1, W2, W3, qw, kw, mag, out_pred, s_state, s_part);
}

// ---------------- Kernel 2: attention tile, A_new, target, err, plasticity --
// 256 blocks = 16 batches x 16 tiles of 8 rows. 256 threads: rr = tid>>5 is
// the row within the tile, c = tid&31; each thread owns m = c+32i, i=0..3.
// All reductions are 32-lane shuffles (no barrier trees). k-slice is staged
// in LDS with stride-65 padding => conflict-free strided reads.
template<bool F32>
__device__ __forceinline__ void k2_body(
    const float* qw, const float* kw, const float* predw,
    const void* noiseA, const void* Aold, const void* outp,
    const void* eye, const void* stomach, const void* Ebase,
    float* errw, float* plw, float* stats,
    float* out_target, float* out_A,
    float* s_k, float* s_q, float* s_A)
{
  const int bidx = blockIdx.x;
  const int b = bidx >> 4;
  const int n0 = (bidx & 15) * 8;
  const int tid = threadIdx.x;

  { // stage k slice [128][64] -> LDS [128][65] (padded), q rows [8][64]
    const float* kwb = kw + (size_t)b * 8192;
    #pragma unroll
    for (int it = 0; it < 8; ++it) {
      const int idx = it*256 + tid;          // float4 index, 0..2047
      const int m = idx >> 4, dq = idx & 15;
      const float4 v = *(const float4*)(kwb + (size_t)idx * 4);
      float* dst = &s_k[m*65 + dq*4];
      dst[0] = v.x; dst[1] = v.y; dst[2] = v.z; dst[3] = v.w;
    }
    if (tid < 128) {
      const int rr = tid >> 4, dq = tid & 15;
      *(float4*)&s_q[rr*64 + dq*4] =
          *(const float4*)(qw + ((size_t)(b*128 + n0 + rr))*64 + dq*4);
    }
  }
  __syncthreads();

  const int rr = tid >> 5, c = tid & 31;
  const int n = n0 + rr;
  const size_t node = (size_t)b*128 + n;

  // raw_A[n, m] for m = c + 32*i
  float acc[4] = {0.f, 0.f, 0.f, 0.f};
  {
    const float* qrow = s_q + rr*64;
    #pragma unroll 8
    for (int j = 0; j < 64; ++j) {
      const float qv = qrow[j];
      acc[0] += qv * s_k[(c     )*65 + j];
      acc[1] += qv * s_k[(c + 32)*65 + j];
      acc[2] += qv * s_k[(c + 64)*65 + j];
      acc[3] += qv * s_k[(c + 96)*65 + j];
    }
  }
  float raw[4];
  #pragma unroll
  for (int i = 0; i < 4; ++i)
    raw[i] = acc[i]*0.125f + 1e-5f*ld<F32>(noiseA, node*128 + c + 32*i);

  // row softmax over 128 via 32-lane shuffles (4 values/lane)
  float rmx = fmaxf(fmaxf(raw[0], raw[1]), fmaxf(raw[2], raw[3]));
  #pragma unroll
  for (int s = 16; s >= 1; s >>= 1) rmx = fmaxf(rmx, __shfl_xor(rmx, s, 64));
  float e[4], S = 0.f;
  #pragma unroll
  for (int i = 0; i < 4; ++i) { e[i] = expf(raw[i] - rmx); S += e[i]; }
  #pragma unroll
  for (int s = 16; s >= 1; s >>= 1) S += __shfl_xor(S, s, 64);
  float ek[4], Sk = 0.f;
  #pragma unroll
  for (int i = 0; i < 4; ++i) {
    const float Pd = e[i] / S;
    ek[i] = ((Pd > 0.007751937984496124f) || (raw[i] == rmx)) ? e[i] : 0.f;  // 1/(N+1)
    Sk += ek[i];
  }
  #pragma unroll
  for (int s = 16; s >= 1; s >>= 1) Sk += __shfl_xor(Sk, s, 64);
  #pragma unroll
  for (int i = 0; i < 4; ++i) {
    const int m = c + 32*i;
    const float P = ek[i] / Sk;
    const float An = (n < 2) ? 0.f
                   : 0.99f * ld<F32>(Aold, node*128 + m) + 0.01f * P;
    out_A[node*128 + m] = An;
    s_A[rr*128 + m] = An;
  }
  __syncthreads();

  // target row: each thread owns d = c and d = c+32
  float t0, t1;
  if (n == 0) {
    t0 = ld<F32>(eye, (size_t)b*64 + c);
    t1 = ld<F32>(eye, (size_t)b*64 + c + 32);
  } else if (n == 1) {
    t0 = ld<F32>(stomach, (size_t)b*64 + c);
    t1 = ld<F32>(stomach, (size_t)b*64 + c + 32);
  } else {
    t0 = 0.f; t1 = 0.f;
    const float* arow = s_A + rr*128;
    const size_t ob = (size_t)b * 8192;
    #pragma unroll 4
    for (int m = 0; m < 128; ++m) {
      const float a = arow[m];
      t0 += a * ld<F32>(outp, ob + m*64 + c);
      t1 += a * ld<F32>(outp, ob + m*64 + c + 32);
    }
  }
  out_target[node*64 + c]      = t0;
  out_target[node*64 + c + 32] = t1;
  const float e0 = predw[node*64 + c]      - t0;
  const float e1 = predw[node*64 + c + 32] - t1;
  errw[node*64 + c]      = e0;
  errw[node*64 + c + 32] = e1;

  // E_curr = softmax(err over d=64), then plasticity*mask
  float mx = fmaxf(e0, e1);
  #pragma unroll
  for (int s = 16; s >= 1; s >>= 1) mx = fmaxf(mx, __shfl_xor(mx, s, 64));
  const float x0 = expf(e0 - mx), x1 = expf(e1 - mx);
  float ss = x0 + x1;
  #pragma unroll
  for (int s = 16; s >= 1; s >>= 1) ss += __shfl_xor(ss, s, 64);
  plw[node*64 + c]      = plast(x0/ss, ld<F32>(Ebase, node*64 + c));
  plw[node*64 + c + 32] = plast(x1/ss, ld<F32>(Ebase, node*64 + c + 32));

  // global err stats (for std, ddof=1)
  float se = e0 + e1, sq = e0*e0 + e1*e1;
  #pragma unroll
  for (int s = 16; s >= 1; s >>= 1) { se += __shfl_xor(se, s, 64); sq += __shfl_xor(sq, s, 64); }
  if (c == 0) { atomicAdd(&stats[0], se); atomicAdd(&stats[1], sq); }
}

__global__ __launch_bounds__(256) void k2_attn(
    const int* __restrict__ flag,
    const float* __restrict__ qw, const float* __restrict__ kw,
    const float* __restrict__ predw,
    const void* __restrict__ noiseA, const void* __restrict__ Aold,
    const void* __restrict__ outp,
    const void* __restrict__ eye, const void* __restrict__ stomach,
    const void* __restrict__ Ebase,
    float* __restrict__ errw, float* __restrict__ plw,
    float* __restrict__ stats,
    float* __restrict__ out_target, float* __restrict__ out_A)
{
  __shared__ alignas(16) float s_k[128*65];   // padded: conflict-free strided reads
  __shared__ alignas(16) float s_q[8*64];
  __shared__ alignas(16) float s_A[8*128];
  if (*flag) k2_body<true >(qw,kw,predw,noiseA,Aold,outp,eye,stomach,Ebase,errw,plw,stats,out_target,out_A,s_k,s_q,s_A);
  else       k2_body<false>(qw,kw,predw,noiseA,Aold,outp,eye,stomach,Ebase,errw,plw,stats,out_target,out_A,s_k,s_q,s_A);
}

// ---------------- Kernel 3: grads, momentum, W update + row rms-norm ---------
// 512 threads, single pass: thread owns row r = tid>>3, columns lane8*8..+7.
// All 12 dwordx4 loads issue up front; the per-node prologue hides under them.
template<bool F32>
__device__ __forceinline__ void k3_body(
    const float* errw, const float* plw,
    const void* state, const void* n1raw, const void* n2raw,
    const float* mag, const float* stats, const int* stepc,
    const void* W1, const void* W2, const void* W3,
    const void* M1, const void* M2, const void* M3,
    float* oW1, float* oW2, float* oW3,
    float* s_err, float* s_ns, float* s_pe, float* s_c, float* s_g)
{
  const int node = blockIdx.x;
  const int b = node >> 7;
  const int tid = threadIdx.x;
  if (tid < 64) {
    const float e = errw[(size_t)node*64 + tid];
    s_err[tid] = e;
    s_pe[tid]  = plw[(size_t)node*64 + tid] * e;     // pe_i
  } else if (tid < 128) {
    const int i = tid - 64;
    const float S1 = stats[0], S2 = stats[1];
    const float Mn = 131072.f;                       // B*N*D
    const float var = (S2 - S1*S1/Mn) / (Mn - 1.f);  // ddof=1
    const float stdv = sqrtf(fmaxf(var, 0.f));
    s_ns[i] = ld<F32>(state, (size_t)node*64 + i)
            + ld<F32>(n1raw, (size_t)node*64 + i) / (1.f + mag[b])
            + ld<F32>(n2raw, (size_t)node*64 + i) * stdv * 0.8f;  // NOISE_SCALE
  } else if (tid < 192) {
    const int i = tid - 128;
    const float sc = (float)stepc[0] + 1.f;
    const float center = fmodf(sc * 0.5f, 64.f);     // SPEED
    float diff = fabsf((float)i - center);
    diff = fminf(diff, 64.f - diff);
    s_g[i] = expf(-diff*diff * (1.f/0.020001f));     // 2*WIDTH^2+1e-6
  }

  const int r = tid >> 3;
  const int l8 = tid & 7;
  const size_t off = (size_t)node*4096 + (size_t)r*64 + (size_t)l8*8;
  float w1v[8], w2v[8], w3v[8], m1v[8], m2v[8], m3v[8];
  ld8  <F32>(W1, off, w1v); ld8  <F32>(W2, off, w2v); ld8  <F32>(W3, off, w3v);
  ld8nt<F32>(M1, off, m1v); ld8nt<F32>(M2, off, m2v); ld8nt<F32>(M3, off, m3v);
  __syncthreads();

  if (tid < 64) {
    float e2 = s_err[tid]*s_err[tid];
    float n2 = s_ns[tid]*s_ns[tid];
    #pragma unroll
    for (int s = 32; s; s >>= 1) { e2 += __shfl_xor(e2, s, 64); n2 += __shfl_xor(n2, s, 64); }
    // rms_norm(lg) factorizes: mean(lg^2) = (sum err^2)(sum ns^2)/4096
    s_c[tid] = -s_ns[tid] * rsqrtf(e2 * n2 * (1.f/4096.f) + 1e-6f);
  }
  __syncthreads();

  const float pe = s_pe[r];
  float t1[8], t2[8], t3[8];
  float ss1 = 0.f, ss2 = 0.f, ss3 = 0.f;
  #pragma unroll
  for (int cc = 0; cc < 8; ++cc) {
    const int j = l8*8 + cc;
    const float lgterm = pe * s_c[j];                 // p_i * lg_ij
    const float g = s_g[j];
    const float g1 = lgterm + 0.01f*w3v[cc] - 0.01f*w1v[cc];  // LAT_DECAY, WD
    const float g2 = lgterm + 0.01f*w1v[cc] - 0.01f*w2v[cc];
    const float g3 = lgterm + 0.01f*w2v[cc] - 0.01f*w3v[cc];
    const float v1 = w1v[cc] + 0.0033f*(0.4f*m1v[cc] + 0.6f*g1*g); // LR, MOMENTUM
    const float v2 = w2v[cc] + 0.0033f*(0.4f*m2v[cc] + 0.6f*g2*g);
    const float v3 = w3v[cc] + 0.0033f*(0.4f*m3v[cc] + 0.6f*g3*g);
    t1[cc] = v1; t2[cc] = v2; t3[cc] = v3;
    ss1 += v1*v1; ss2 += v2*v2; ss3 += v3*v3;
  }
  #pragma unroll
  for (int s = 1; s <= 4; s <<= 1) {
    ss1 += __shfl_xor(ss1, s, 64);
    ss2 += __shfl_xor(ss2, s, 64);
    ss3 += __shfl_xor(ss3, s, 64);
  }
  const float r1 = rsqrtf(ss1*(1.f/64.f) + 1e-6f);    // row rms over j
  const float r2 = rsqrtf(ss2*(1.f/64.f) + 1e-6f);
  const float r3 = rsqrtf(ss3*(1.f/64.f) + 1e-6f);
  f32x4 o;
  o[0]=t1[0]*r1; o[1]=t1[1]*r1; o[2]=t1[2]*r1; o[3]=t1[3]*r1;
  __builtin_nontemporal_store(o, (f32x4*)(oW1 + off));
  o[0]=t1[4]*r1; o[1]=t1[5]*r1; o[2]=t1[6]*r1; o[3]=t1[7]*r1;
  __builtin_nontemporal_store(o, (f32x4*)(oW1 + off + 4));
  o[0]=t2[0]*r2; o[1]=t2[1]*r2; o[2]=t2[2]*r2; o[3]=t2[3]*r2;
  __builtin_nontemporal_store(o, (f32x4*)(oW2 + off));
  o[0]=t2[4]*r2; o[1]=t2[5]*r2; o[2]=t2[6]*r2; o[3]=t2[7]*r2;
  __builtin_nontemporal_store(o, (f32x4*)(oW2 + off + 4));
  o[0]=t3[0]*r3; o[1]=t3[1]*r3; o[2]=t3[2]*r3; o[3]=t3[3]*r3;
  __builtin_nontemporal_store(o, (f32x4*)(oW3 + off));
  o[0]=t3[4]*r3; o[1]=t3[5]*r3; o[2]=t3[6]*r3; o[3]=t3[7]*r3;
  __builtin_nontemporal_store(o, (f32x4*)(oW3 + off + 4));
}

__global__ __launch_bounds__(512, 2) void k3_update(
    const int* __restrict__ flag,
    const float* __restrict__ errw, const float* __restrict__ plw,
    const void* __restrict__ state, const void* __restrict__ n1raw,
    const void* __restrict__ n2raw,
    const float* __restrict__ mag, const float* __restrict__ stats,
    const int* __restrict__ stepc,
    const void* __restrict__ W1, const void* __restrict__ W2,
    const void* __restrict__ W3,
    const void* __restrict__ M1, const void* __restrict__ M2,
    const void* __restrict__ M3,
    float* __restrict__ oW1, float* __restrict__ oW2, float* __restrict__ oW3)
{
  __shared__ alignas(16) float s_err[64], s_ns[64], s_pe[64], s_c[64], s_g[64];
  if (*flag) k3_body<true >(errw,plw,state,n1raw,n2raw,mag,stats,stepc,W1,W2,W3,M1,M2,M3,oW1,oW2,oW3,s_err,s_ns,s_pe,s_c,s_g);
  else       k3_body<false>(errw,plw,state,n1raw,n2raw,mag,stats,stepc,W1,W2,W3,M1,M2,M3,oW1,oW2,oW3,s_err,s_ns,s_pe,s_c,s_g);
}

extern "C" void kernel_launch(void* const* d_in, const int* in_sizes, int n_in,
                              void* d_out, int out_size, void* d_ws, size_t ws_size,
                              hipStream_t stream) {
  const void* eye     = d_in[0];
  const void* stomach = d_in[1];
  const void* state   = d_in[2];
  const void* outp    = d_in[3];
  const void* W1      = d_in[4];
  const void* W2      = d_in[5];
  const void* W3      = d_in[6];
  const void* M1      = d_in[7];
  const void* M2      = d_in[8];
  const void* M3      = d_in[9];
  const void* Ebase   = d_in[10];
  const void* Aold    = d_in[11];
  const void* noiseA  = d_in[12];
  const void* n1raw   = d_in[13];
  const void* n2raw   = d_in[14];
  const int*  stepc   = (const int*)d_in[15];

  float* ws    = (float*)d_ws;
  float* qw    = ws;
  float* kw    = ws + 131072;
  float* errw  = ws + 262144;
  float* plw   = ws + 393216;
  float* mag   = ws + 524288;
  float* stats = ws + 524304;
  int*   flag  = (int*)(ws + 524306);

  float* out        = (float*)d_out;
  float* out_pred   = out;                 // (B,N,D)
  float* out_target = out + 131072;        // (B,N,D)
  float* out_A      = out + 262144;        // (B,N,N)
  float* oW1        = out + 524288;        // (B,N,D,D)
  float* oW2        = out + 8912896;
  float* oW3        = out + 17301504;

  hipMemsetAsync(mag, 0, 18 * sizeof(float), stream);
  k1_qkpred<<<2048, 256, 0, stream>>>(state, W1, W2, W3, qw, kw, mag, out_pred, flag);
  k2_attn<<<256, 256, 0, stream>>>(flag, qw, kw, out_pred, noiseA, Aold, outp,
                                   eye, stomach, Ebase, errw, plw, stats,
                                   out_target, out_A);
  k3_update<<<2048, 512, 0, stream>>>(flag, errw, plw, state, n1raw, n2raw, mag, stats,
                                      stepc, W1, W2, W3, M1, M2, M3, oW1, oW2, oW3);
}